// Round 19
// baseline (439.219 us; speedup 1.0000x reference)
//
#include <hip/hip_runtime.h>
#include <hip/hip_bf16.h>

#define BB 4
#define TT 2048
#define SSZ 2048
#define DQq 512
#define NH 8
#define HDim 64

typedef __attribute__((ext_vector_type(8))) short short8;
typedef __attribute__((ext_vector_type(4))) short bf16x4;
typedef __attribute__((ext_vector_type(4))) float f32x4;
typedef __attribute__((ext_vector_type(4))) int i32x4;

__device__ __forceinline__ short f2bf(float f) {
    union { float f; unsigned u; } v; v.f = f;
    unsigned r = v.u + 0x7fffu + ((v.u >> 16) & 1u);
    return (short)(r >> 16);
}

// ---------------- weight transpose + bf16 convert: W[Kd][512] -> Wt[512][Kd]
// (verified round 5)
__global__ void wt_kernel(const float* __restrict__ W, short* __restrict__ Wt, int Kd) {
    int tid = blockIdx.x * 256 + threadIdx.x;
    int n = tid / Kd, k = tid - n * Kd;
    Wt[tid] = f2bf(W[(size_t)k * DQq + n]);
}

// ---------------- projection GEMM v2: 128x64 tile, 4 waves as 2x2 (64x32
// quadrants), 8 MFMA : 6 ds_read per K-step (was 4:4 at 64x64). Fragment
// reads, epilogue scatter, and per-output MFMA accumulation order identical
// to the round-5-verified kernel -> bit-identical outputs.
template<int MODE, bool IN_BF16>
__global__ __launch_bounds__(256) void gemm_proj(
    const void* __restrict__ Xv, const short* __restrict__ Wt,
    const float* __restrict__ bias, void* __restrict__ Out, int Kd)
{
    __shared__ short As[128 * 40];
    __shared__ short Bs[64 * 40];
    int tid = threadIdx.x;
    int wave = tid >> 6, lane = tid & 63;
    int g = lane >> 4, r = lane & 15;
    int wm = wave >> 1, wn = wave & 1;
    int m0 = blockIdx.x * 128, n0 = blockIdx.y * 64;

    const float* Xf = (const float*)Xv;
    const short* Xb = (const short*)Xv;

    f32x4 acc[4][2];
    for (int a = 0; a < 4; ++a)
        for (int b2 = 0; b2 < 2; ++b2) acc[a][b2] = (f32x4){0.f,0.f,0.f,0.f};

    int lrow = tid >> 1, lk = (tid & 1) * 16;   // A: 128 rows, 2 threads/row
    int brow = tid >> 2, bk = (tid & 3) * 8;    // B: 64 rows, 4 threads/row

    for (int k0 = 0; k0 < Kd; k0 += 32) {
        short8 av0, av1;
        if (IN_BF16) {
            av0 = *(const short8*)(Xb + (size_t)(m0 + lrow) * Kd + k0 + lk);
            av1 = *(const short8*)(Xb + (size_t)(m0 + lrow) * Kd + k0 + lk + 8);
        } else {
            const f32x4* p = (const f32x4*)(Xf + (size_t)(m0 + lrow) * Kd + k0 + lk);
            f32x4 x0 = p[0], x1 = p[1], x2 = p[2], x3 = p[3];
            av0[0]=f2bf(x0[0]); av0[1]=f2bf(x0[1]); av0[2]=f2bf(x0[2]); av0[3]=f2bf(x0[3]);
            av0[4]=f2bf(x1[0]); av0[5]=f2bf(x1[1]); av0[6]=f2bf(x1[2]); av0[7]=f2bf(x1[3]);
            av1[0]=f2bf(x2[0]); av1[1]=f2bf(x2[1]); av1[2]=f2bf(x2[2]); av1[3]=f2bf(x2[3]);
            av1[4]=f2bf(x3[0]); av1[5]=f2bf(x3[1]); av1[6]=f2bf(x3[2]); av1[7]=f2bf(x3[3]);
        }
        *(short8*)(As + lrow * 40 + lk) = av0;
        *(short8*)(As + lrow * 40 + lk + 8) = av1;
        short8 bv = *(const short8*)(Wt + (size_t)(n0 + brow) * Kd + k0 + bk);
        *(short8*)(Bs + brow * 40 + bk) = bv;
        __syncthreads();
        short8 af[4], bf[2];
        #pragma unroll
        for (int mi = 0; mi < 4; ++mi)
            af[mi] = *(short8*)(As + (wm*64 + mi*16 + r) * 40 + g*8);
        #pragma unroll
        for (int ni = 0; ni < 2; ++ni)
            bf[ni] = *(short8*)(Bs + (wn*32 + ni*16 + r) * 40 + g*8);
        #pragma unroll
        for (int mi = 0; mi < 4; ++mi)
            #pragma unroll
            for (int ni = 0; ni < 2; ++ni)
                acc[mi][ni] = __builtin_amdgcn_mfma_f32_16x16x32_bf16(af[mi], bf[ni], acc[mi][ni], 0, 0, 0);
        __syncthreads();
    }

    for (int mi = 0; mi < 4; ++mi)
      for (int ni = 0; ni < 2; ++ni)
        for (int i = 0; i < 4; ++i) {
            int m = m0 + wm*64 + mi*16 + g*4 + i;
            int n = n0 + wn*32 + ni*16 + r;
            float v = acc[mi][ni][i] + bias[n];
            if (MODE == 0) {
                int b = m >> 11, t = m & 2047, h = n >> 6, hd = n & 63;
                ((short*)Out)[((((size_t)b*NH + h)*TT + t) << 6) + hd] = f2bf(v);
            } else if (MODE == 1) {
                int b = m >> 11, t = m & 2047, h = n >> 6, hd = n & 63;
                ((short*)Out)[(((size_t)b*NH + h)*HDim + hd)*SSZ + t] = f2bf(v);
            } else {
                ((float*)Out)[(size_t)m * DQq + n] = v;
            }
        }
}

// ---------------- FUSED attention v7 (r18-verified, byte-identical)
#define WPITCH 264

__global__ __launch_bounds__(256) void attn_pv(
    const short* __restrict__ Q, const short* __restrict__ K,
    const short* __restrict__ Vt,
    const int* __restrict__ kpm, const float* __restrict__ amask,
    float* __restrict__ attnW, float* __restrict__ AO)
{
    __shared__ float s_wl[4][64];
    __shared__ float s_li[64];
    __shared__ short wch[64][WPITCH];

    int tid = threadIdx.x;
    int wave = tid >> 6, lane = tid & 63;
    int g = lane >> 4, r = lane & 15;
    int t0 = blockIdx.x * 64;
    int bh = blockIdx.y;
    int b = bh >> 3, h = bh & 7;

    const short* Qp = Q + ((size_t)bh * TT + t0) * HDim;
    const short* Kp = K + (size_t)bh * SSZ * HDim;

    short8 qf[4][2];
    #pragma unroll
    for (int tt = 0; tt < 4; ++tt) {
        qf[tt][0] = *(const short8*)(Qp + (size_t)(tt * 16 + r) * HDim + g * 8);
        qf[tt][1] = *(const short8*)(Qp + (size_t)(tt * 16 + r) * HDim + 32 + g * 8);
    }

    const float* amrow[4];
    #pragma unroll
    for (int tt = 0; tt < 4; ++tt)
        amrow[tt] = amask + (size_t)(t0 + tt * 16 + r) * SSZ;
    const int* kpmb = kpm + b * SSZ;

    // ---- phase 1 (transposed, 4 t-tiles): denominators
    int ws0 = wave * 512;
    float lrun[4] = {0.f, 0.f, 0.f, 0.f};
    for (int it = 0; it < 16; ++it) {
        int col0 = ws0 + it * 32;
        const short* kpA = Kp + (size_t)(col0 + r) * HDim;
        const short* kpB = Kp + (size_t)(col0 + 16 + r) * HDim;
        short8 kA0 = *(const short8*)(kpA + g * 8);
        short8 kA1 = *(const short8*)(kpA + 32 + g * 8);
        short8 kB0 = *(const short8*)(kpB + g * 8);
        short8 kB1 = *(const short8*)(kpB + 32 + g * 8);
        i32x4 okA = *(const i32x4*)(kpmb + col0 + g * 4);
        i32x4 okB = *(const i32x4*)(kpmb + col0 + 16 + g * 4);
        #pragma unroll
        for (int tt = 0; tt < 4; ++tt) {
            f32x4 sA = (f32x4){0.f,0.f,0.f,0.f}, sB = (f32x4){0.f,0.f,0.f,0.f};
            sA = __builtin_amdgcn_mfma_f32_16x16x32_bf16(kA0, qf[tt][0], sA, 0, 0, 0);
            sA = __builtin_amdgcn_mfma_f32_16x16x32_bf16(kA1, qf[tt][1], sA, 0, 0, 0);
            sB = __builtin_amdgcn_mfma_f32_16x16x32_bf16(kB0, qf[tt][0], sB, 0, 0, 0);
            sB = __builtin_amdgcn_mfma_f32_16x16x32_bf16(kB1, qf[tt][1], sB, 0, 0, 0);
            f32x4 amA = *(const f32x4*)(amrow[tt] + col0 + g * 4);
            f32x4 amB = *(const f32x4*)(amrow[tt] + col0 + 16 + g * 4);
            for (int i = 0; i < 4; ++i) {
                float vA = sA[i] * 0.125f + amA[i]; if (okA[i] == 0) vA = -1e30f;
                lrun[tt] += __expf(vA);
                float vB = sB[i] * 0.125f + amB[i]; if (okB[i] == 0) vB = -1e30f;
                lrun[tt] += __expf(vB);
            }
        }
    }
    #pragma unroll
    for (int tt = 0; tt < 4; ++tt) {
        lrun[tt] += __shfl_xor(lrun[tt], 16);
        lrun[tt] += __shfl_xor(lrun[tt], 32);
    }
    if (lane < 16) {
        #pragma unroll
        for (int tt = 0; tt < 4; ++tt)
            s_wl[wave][tt * 16 + lane] = lrun[tt];
    }
    __syncthreads();
    if (tid < 64)
        s_li[tid] = 1.0f / (s_wl[0][tid] + s_wl[1][tid] + s_wl[2][tid] + s_wl[3][tid]);
    __syncthreads();

    float li[4];
    float* wrow[4];
    #pragma unroll
    for (int tt = 0; tt < 4; ++tt) {
        li[tt] = s_li[tt * 16 + r];
        wrow[tt] = attnW + ((size_t)bh * TT + t0 + tt * 16 + r) * SSZ;
    }
    const short* vrow = Vt + ((size_t)bh * HDim + wave * 16 + r) * SSZ;
    f32x4 oacc[4];
    #pragma unroll
    for (int tt = 0; tt < 4; ++tt) oacc[tt] = (f32x4){0.f, 0.f, 0.f, 0.f};

    // ---- phases 2+3 per 256-col chunk
    for (int ch = 0; ch < 8; ++ch) {
        for (int it = 0; it < 2; ++it) {
            int col0 = ch * 256 + wave * 64 + it * 32;
            const short* kpA = Kp + (size_t)(col0 + r) * HDim;
            const short* kpB = Kp + (size_t)(col0 + 16 + r) * HDim;
            short8 kA0 = *(const short8*)(kpA + g * 8);
            short8 kA1 = *(const short8*)(kpA + 32 + g * 8);
            short8 kB0 = *(const short8*)(kpB + g * 8);
            short8 kB1 = *(const short8*)(kpB + 32 + g * 8);
            i32x4 okA = *(const i32x4*)(kpmb + col0 + g * 4);
            i32x4 okB = *(const i32x4*)(kpmb + col0 + 16 + g * 4);
            int lcol = wave * 64 + it * 32;
            #pragma unroll
            for (int tt = 0; tt < 4; ++tt) {
                f32x4 sA = (f32x4){0.f,0.f,0.f,0.f}, sB = (f32x4){0.f,0.f,0.f,0.f};
                sA = __builtin_amdgcn_mfma_f32_16x16x32_bf16(kA0, qf[tt][0], sA, 0, 0, 0);
                sA = __builtin_amdgcn_mfma_f32_16x16x32_bf16(kA1, qf[tt][1], sA, 0, 0, 0);
                sB = __builtin_amdgcn_mfma_f32_16x16x32_bf16(kB0, qf[tt][0], sB, 0, 0, 0);
                sB = __builtin_amdgcn_mfma_f32_16x16x32_bf16(kB1, qf[tt][1], sB, 0, 0, 0);
                f32x4 amA = *(const f32x4*)(amrow[tt] + col0 + g * 4);
                f32x4 amB = *(const f32x4*)(amrow[tt] + col0 + 16 + g * 4);
                f32x4 wA, wB;
                bf16x4 pA, pB;
                for (int i = 0; i < 4; ++i) {
                    float vA = sA[i] * 0.125f + amA[i]; if (okA[i] == 0) vA = -1e30f;
                    wA[i] = __expf(vA) * li[tt]; pA[i] = f2bf(wA[i]);
                    float vB = sB[i] * 0.125f + amB[i]; if (okB[i] == 0) vB = -1e30f;
                    wB[i] = __expf(vB) * li[tt]; pB[i] = f2bf(wB[i]);
                }
                *(f32x4*)(wrow[tt] + col0 + g * 4) = wA;
                *(f32x4*)(wrow[tt] + col0 + 16 + g * 4) = wB;
                *(bf16x4*)&wch[tt * 16 + r][lcol + g * 4] = pA;
                *(bf16x4*)&wch[tt * 16 + r][lcol + 16 + g * 4] = pB;
            }
        }
        short8 vf[8];
        #pragma unroll
        for (int s = 0; s < 8; ++s)
            vf[s] = *(const short8*)(vrow + ch * 256 + s * 32 + g * 8);

        __syncthreads();

        #pragma unroll
        for (int s = 0; s < 8; ++s) {
            #pragma unroll
            for (int tt = 0; tt < 4; ++tt) {
                short8 wf = *(const short8*)&wch[tt * 16 + r][s * 32 + g * 8];
                oacc[tt] = __builtin_amdgcn_mfma_f32_16x16x32_bf16(wf, vf[s], oacc[tt], 0, 0, 0);
            }
        }
        __syncthreads();
    }

    #pragma unroll
    for (int tt = 0; tt < 4; ++tt)
        for (int i = 0; i < 4; ++i)
            AO[((size_t)(b * TT + t0 + tt * 16 + g * 4 + i)) * DQq + h * HDim + wave * 16 + r] = oacc[tt][i];
}

extern "C" void kernel_launch(void* const* d_in, const int* in_sizes, int n_in,
                              void* d_out, int out_size, void* d_ws, size_t ws_size,
                              hipStream_t stream)
{
    const float* query = (const float*)d_in[0];
    const float* key   = (const float*)d_in[1];
    const float* value = (const float*)d_in[2];
    const int*   kpm   = (const int*)d_in[3];
    const float* amask = (const float*)d_in[4];
    const float* Wq = (const float*)d_in[5];
    const float* bq = (const float*)d_in[6];
    const float* Wk = (const float*)d_in[7];
    const float* bk = (const float*)d_in[8];
    const float* Wv = (const float*)d_in[9];
    const float* bv = (const float*)d_in[10];
    const float* Wo = (const float*)d_in[11];
    const float* bo = (const float*)d_in[12];

    char* ws = (char*)d_ws;
    short* WqT = (short*)ws;  ws += (size_t)512 * 512 * 2;
    short* WkT = (short*)ws;  ws += (size_t)512 * 1024 * 2;
    short* WvT = (short*)ws;  ws += (size_t)512 * 1024 * 2;
    short* WoT = (short*)ws;  ws += (size_t)512 * 512 * 2;
    short* Qh  = (short*)ws;  ws += (size_t)BB * NH * TT * HDim * 2;
    short* Kh  = (short*)ws;  ws += (size_t)BB * NH * SSZ * HDim * 2;
    short* Vth = (short*)ws;  ws += (size_t)BB * NH * HDim * SSZ * 2;
    float* AOf = (float*)ws;  ws += (size_t)BB * TT * DQq * 4;

    float* out0  = (float*)d_out;
    float* attnW = out0 + (size_t)BB * TT * DQq;

    wt_kernel<<<(512*512)/256, 256, 0, stream>>>(Wq, WqT, 512);
    wt_kernel<<<(1024*512)/256, 256, 0, stream>>>(Wk, WkT, 1024);
    wt_kernel<<<(1024*512)/256, 256, 0, stream>>>(Wv, WvT, 1024);
    wt_kernel<<<(512*512)/256, 256, 0, stream>>>(Wo, WoT, 512);

    dim3 gp(8192 / 128, 512 / 64);
    gemm_proj<0, false><<<gp, 256, 0, stream>>>(query, WqT, bq, Qh, 512);
    gemm_proj<0, false><<<gp, 256, 0, stream>>>(key,   WkT, bk, Kh, 1024);
    gemm_proj<1, false><<<gp, 256, 0, stream>>>(value, WvT, bv, Vth, 1024);

    dim3 ga(TT / 64, BB * NH);
    attn_pv<<<ga, 256, 0, stream>>>(Qh, Kh, Vth, kpm, amask, attnW, AOf);

    gemm_proj<2, false><<<gp, 256, 0, stream>>>(AOf, WoT, bo, out0, 512);
}

// Round 20
// 352.878 us; speedup vs baseline: 1.2447x; 1.2447x over previous
//
#include <hip/hip_runtime.h>
#include <hip/hip_bf16.h>

#define BB 4
#define TT 2048
#define SSZ 2048
#define DQq 512
#define NH 8
#define HDim 64

typedef __attribute__((ext_vector_type(8))) short short8;
typedef __attribute__((ext_vector_type(4))) short bf16x4;
typedef __attribute__((ext_vector_type(4))) float f32x4;
typedef __attribute__((ext_vector_type(4))) int i32x4;

__device__ __forceinline__ short f2bf(float f) {
    union { float f; unsigned u; } v; v.f = f;
    unsigned r = v.u + 0x7fffu + ((v.u >> 16) & 1u);
    return (short)(r >> 16);
}

// ---------------- weight transpose + bf16 convert: W[Kd][512] -> Wt[512][Kd]
// (verified round 5)
__global__ void wt_kernel(const float* __restrict__ W, short* __restrict__ Wt, int Kd) {
    int tid = blockIdx.x * 256 + threadIdx.x;
    int n = tid / Kd, k = tid - n * Kd;
    Wt[tid] = f2bf(W[(size_t)k * DQq + n]);
}

// ---------------- projection GEMM (round-5-verified 64x64; r19's 128x64
// regressed 419->439 -> reverted byte-identical)
template<int MODE, bool IN_BF16>
__global__ __launch_bounds__(256) void gemm_proj(
    const void* __restrict__ Xv, const short* __restrict__ Wt,
    const float* __restrict__ bias, void* __restrict__ Out, int Kd)
{
    __shared__ short As[64 * 40];
    __shared__ short Bs[64 * 40];
    int tid = threadIdx.x;
    int wave = tid >> 6, lane = tid & 63;
    int g = lane >> 4, r = lane & 15;
    int wm = wave >> 1, wn = wave & 1;
    int m0 = blockIdx.x * 64, n0 = blockIdx.y * 64;

    const float* Xf = (const float*)Xv;
    const short* Xb = (const short*)Xv;

    f32x4 acc[2][2];
    for (int a = 0; a < 2; ++a) for (int b2 = 0; b2 < 2; ++b2) acc[a][b2] = (f32x4){0.f,0.f,0.f,0.f};

    int lrow = tid >> 2, lk = (tid & 3) * 8;

    for (int k0 = 0; k0 < Kd; k0 += 32) {
        short8 av;
        if (IN_BF16) {
            av = *(const short8*)(Xb + (size_t)(m0 + lrow) * Kd + k0 + lk);
        } else {
            const f32x4* p = (const f32x4*)(Xf + (size_t)(m0 + lrow) * Kd + k0 + lk);
            f32x4 x0 = p[0], x1 = p[1];
            av[0]=f2bf(x0[0]); av[1]=f2bf(x0[1]); av[2]=f2bf(x0[2]); av[3]=f2bf(x0[3]);
            av[4]=f2bf(x1[0]); av[5]=f2bf(x1[1]); av[6]=f2bf(x1[2]); av[7]=f2bf(x1[3]);
        }
        *(short8*)(As + lrow * 40 + lk) = av;
        short8 bv = *(const short8*)(Wt + (size_t)(n0 + lrow) * Kd + k0 + lk);
        *(short8*)(Bs + lrow * 40 + lk) = bv;
        __syncthreads();
        short8 af[2], bf[2];
        for (int mi = 0; mi < 2; ++mi)
            af[mi] = *(short8*)(As + (wm*32 + mi*16 + r) * 40 + g*8);
        for (int ni = 0; ni < 2; ++ni)
            bf[ni] = *(short8*)(Bs + (wn*32 + ni*16 + r) * 40 + g*8);
        for (int mi = 0; mi < 2; ++mi)
            for (int ni = 0; ni < 2; ++ni)
                acc[mi][ni] = __builtin_amdgcn_mfma_f32_16x16x32_bf16(af[mi], bf[ni], acc[mi][ni], 0, 0, 0);
        __syncthreads();
    }

    for (int mi = 0; mi < 2; ++mi)
      for (int ni = 0; ni < 2; ++ni)
        for (int i = 0; i < 4; ++i) {
            int m = m0 + wm*32 + mi*16 + g*4 + i;
            int n = n0 + wn*32 + ni*16 + r;
            float v = acc[mi][ni][i] + bias[n];
            if (MODE == 0) {
                int b = m >> 11, t = m & 2047, h = n >> 6, hd = n & 63;
                ((short*)Out)[((((size_t)b*NH + h)*TT + t) << 6) + hd] = f2bf(v);
            } else if (MODE == 1) {
                int b = m >> 11, t = m & 2047, h = n >> 6, hd = n & 63;
                ((short*)Out)[(((size_t)b*NH + h)*HDim + hd)*SSZ + t] = f2bf(v);
            } else {
                ((float*)Out)[(size_t)m * DQq + n] = v;
            }
        }
}

// ---------------- FUSED attention v8: r18 structure + NONTEMPORAL attnW/AO
// stores (pure streaming outputs; keep them out of L2 so K/amask/V stay hot).
// Stored values bit-identical to r18.
#define WPITCH 264

__global__ __launch_bounds__(256) void attn_pv(
    const short* __restrict__ Q, const short* __restrict__ K,
    const short* __restrict__ Vt,
    const int* __restrict__ kpm, const float* __restrict__ amask,
    float* __restrict__ attnW, float* __restrict__ AO)
{
    __shared__ float s_wl[4][64];
    __shared__ float s_li[64];
    __shared__ short wch[64][WPITCH];

    int tid = threadIdx.x;
    int wave = tid >> 6, lane = tid & 63;
    int g = lane >> 4, r = lane & 15;
    int t0 = blockIdx.x * 64;
    int bh = blockIdx.y;
    int b = bh >> 3, h = bh & 7;

    const short* Qp = Q + ((size_t)bh * TT + t0) * HDim;
    const short* Kp = K + (size_t)bh * SSZ * HDim;

    short8 qf[4][2];
    #pragma unroll
    for (int tt = 0; tt < 4; ++tt) {
        qf[tt][0] = *(const short8*)(Qp + (size_t)(tt * 16 + r) * HDim + g * 8);
        qf[tt][1] = *(const short8*)(Qp + (size_t)(tt * 16 + r) * HDim + 32 + g * 8);
    }

    const float* amrow[4];
    #pragma unroll
    for (int tt = 0; tt < 4; ++tt)
        amrow[tt] = amask + (size_t)(t0 + tt * 16 + r) * SSZ;
    const int* kpmb = kpm + b * SSZ;

    // ---- phase 1 (transposed, 4 t-tiles): denominators
    int ws0 = wave * 512;
    float lrun[4] = {0.f, 0.f, 0.f, 0.f};
    for (int it = 0; it < 16; ++it) {
        int col0 = ws0 + it * 32;
        const short* kpA = Kp + (size_t)(col0 + r) * HDim;
        const short* kpB = Kp + (size_t)(col0 + 16 + r) * HDim;
        short8 kA0 = *(const short8*)(kpA + g * 8);
        short8 kA1 = *(const short8*)(kpA + 32 + g * 8);
        short8 kB0 = *(const short8*)(kpB + g * 8);
        short8 kB1 = *(const short8*)(kpB + 32 + g * 8);
        i32x4 okA = *(const i32x4*)(kpmb + col0 + g * 4);
        i32x4 okB = *(const i32x4*)(kpmb + col0 + 16 + g * 4);
        #pragma unroll
        for (int tt = 0; tt < 4; ++tt) {
            f32x4 sA = (f32x4){0.f,0.f,0.f,0.f}, sB = (f32x4){0.f,0.f,0.f,0.f};
            sA = __builtin_amdgcn_mfma_f32_16x16x32_bf16(kA0, qf[tt][0], sA, 0, 0, 0);
            sA = __builtin_amdgcn_mfma_f32_16x16x32_bf16(kA1, qf[tt][1], sA, 0, 0, 0);
            sB = __builtin_amdgcn_mfma_f32_16x16x32_bf16(kB0, qf[tt][0], sB, 0, 0, 0);
            sB = __builtin_amdgcn_mfma_f32_16x16x32_bf16(kB1, qf[tt][1], sB, 0, 0, 0);
            f32x4 amA = *(const f32x4*)(amrow[tt] + col0 + g * 4);
            f32x4 amB = *(const f32x4*)(amrow[tt] + col0 + 16 + g * 4);
            for (int i = 0; i < 4; ++i) {
                float vA = sA[i] * 0.125f + amA[i]; if (okA[i] == 0) vA = -1e30f;
                lrun[tt] += __expf(vA);
                float vB = sB[i] * 0.125f + amB[i]; if (okB[i] == 0) vB = -1e30f;
                lrun[tt] += __expf(vB);
            }
        }
    }
    #pragma unroll
    for (int tt = 0; tt < 4; ++tt) {
        lrun[tt] += __shfl_xor(lrun[tt], 16);
        lrun[tt] += __shfl_xor(lrun[tt], 32);
    }
    if (lane < 16) {
        #pragma unroll
        for (int tt = 0; tt < 4; ++tt)
            s_wl[wave][tt * 16 + lane] = lrun[tt];
    }
    __syncthreads();
    if (tid < 64)
        s_li[tid] = 1.0f / (s_wl[0][tid] + s_wl[1][tid] + s_wl[2][tid] + s_wl[3][tid]);
    __syncthreads();

    float li[4];
    float* wrow[4];
    #pragma unroll
    for (int tt = 0; tt < 4; ++tt) {
        li[tt] = s_li[tt * 16 + r];
        wrow[tt] = attnW + ((size_t)bh * TT + t0 + tt * 16 + r) * SSZ;
    }
    const short* vrow = Vt + ((size_t)bh * HDim + wave * 16 + r) * SSZ;
    f32x4 oacc[4];
    #pragma unroll
    for (int tt = 0; tt < 4; ++tt) oacc[tt] = (f32x4){0.f, 0.f, 0.f, 0.f};

    // ---- phases 2+3 per 256-col chunk
    for (int ch = 0; ch < 8; ++ch) {
        for (int it = 0; it < 2; ++it) {
            int col0 = ch * 256 + wave * 64 + it * 32;
            const short* kpA = Kp + (size_t)(col0 + r) * HDim;
            const short* kpB = Kp + (size_t)(col0 + 16 + r) * HDim;
            short8 kA0 = *(const short8*)(kpA + g * 8);
            short8 kA1 = *(const short8*)(kpA + 32 + g * 8);
            short8 kB0 = *(const short8*)(kpB + g * 8);
            short8 kB1 = *(const short8*)(kpB + 32 + g * 8);
            i32x4 okA = *(const i32x4*)(kpmb + col0 + g * 4);
            i32x4 okB = *(const i32x4*)(kpmb + col0 + 16 + g * 4);
            int lcol = wave * 64 + it * 32;
            #pragma unroll
            for (int tt = 0; tt < 4; ++tt) {
                f32x4 sA = (f32x4){0.f,0.f,0.f,0.f}, sB = (f32x4){0.f,0.f,0.f,0.f};
                sA = __builtin_amdgcn_mfma_f32_16x16x32_bf16(kA0, qf[tt][0], sA, 0, 0, 0);
                sA = __builtin_amdgcn_mfma_f32_16x16x32_bf16(kA1, qf[tt][1], sA, 0, 0, 0);
                sB = __builtin_amdgcn_mfma_f32_16x16x32_bf16(kB0, qf[tt][0], sB, 0, 0, 0);
                sB = __builtin_amdgcn_mfma_f32_16x16x32_bf16(kB1, qf[tt][1], sB, 0, 0, 0);
                f32x4 amA = *(const f32x4*)(amrow[tt] + col0 + g * 4);
                f32x4 amB = *(const f32x4*)(amrow[tt] + col0 + 16 + g * 4);
                f32x4 wA, wB;
                bf16x4 pA, pB;
                for (int i = 0; i < 4; ++i) {
                    float vA = sA[i] * 0.125f + amA[i]; if (okA[i] == 0) vA = -1e30f;
                    wA[i] = __expf(vA) * li[tt]; pA[i] = f2bf(wA[i]);
                    float vB = sB[i] * 0.125f + amB[i]; if (okB[i] == 0) vB = -1e30f;
                    wB[i] = __expf(vB) * li[tt]; pB[i] = f2bf(wB[i]);
                }
                __builtin_nontemporal_store(wA, (f32x4*)(wrow[tt] + col0 + g * 4));
                __builtin_nontemporal_store(wB, (f32x4*)(wrow[tt] + col0 + 16 + g * 4));
                *(bf16x4*)&wch[tt * 16 + r][lcol + g * 4] = pA;
                *(bf16x4*)&wch[tt * 16 + r][lcol + 16 + g * 4] = pB;
            }
        }
        short8 vf[8];
        #pragma unroll
        for (int s = 0; s < 8; ++s)
            vf[s] = *(const short8*)(vrow + ch * 256 + s * 32 + g * 8);

        __syncthreads();

        #pragma unroll
        for (int s = 0; s < 8; ++s) {
            #pragma unroll
            for (int tt = 0; tt < 4; ++tt) {
                short8 wf = *(const short8*)&wch[tt * 16 + r][s * 32 + g * 8];
                oacc[tt] = __builtin_amdgcn_mfma_f32_16x16x32_bf16(wf, vf[s], oacc[tt], 0, 0, 0);
            }
        }
        __syncthreads();
    }

    #pragma unroll
    for (int tt = 0; tt < 4; ++tt)
        for (int i = 0; i < 4; ++i)
            __builtin_nontemporal_store(oacc[tt][i],
                AO + ((size_t)(b * TT + t0 + tt * 16 + g * 4 + i)) * DQq + h * HDim + wave * 16 + r);
}

extern "C" void kernel_launch(void* const* d_in, const int* in_sizes, int n_in,
                              void* d_out, int out_size, void* d_ws, size_t ws_size,
                              hipStream_t stream)
{
    const float* query = (const float*)d_in[0];
    const float* key   = (const float*)d_in[1];
    const float* value = (const float*)d_in[2];
    const int*   kpm   = (const int*)d_in[3];
    const float* amask = (const float*)d_in[4];
    const float* Wq = (const float*)d_in[5];
    const float* bq = (const float*)d_in[6];
    const float* Wk = (const float*)d_in[7];
    const float* bk = (const float*)d_in[8];
    const float* Wv = (const float*)d_in[9];
    const float* bv = (const float*)d_in[10];
    const float* Wo = (const float*)d_in[11];
    const float* bo = (const float*)d_in[12];

    char* ws = (char*)d_ws;
    short* WqT = (short*)ws;  ws += (size_t)512 * 512 * 2;
    short* WkT = (short*)ws;  ws += (size_t)512 * 1024 * 2;
    short* WvT = (short*)ws;  ws += (size_t)512 * 1024 * 2;
    short* WoT = (short*)ws;  ws += (size_t)512 * 512 * 2;
    short* Qh  = (short*)ws;  ws += (size_t)BB * NH * TT * HDim * 2;
    short* Kh  = (short*)ws;  ws += (size_t)BB * NH * SSZ * HDim * 2;
    short* Vth = (short*)ws;  ws += (size_t)BB * NH * HDim * SSZ * 2;
    float* AOf = (float*)ws;  ws += (size_t)BB * TT * DQq * 4;

    float* out0  = (float*)d_out;
    float* attnW = out0 + (size_t)BB * TT * DQq;

    wt_kernel<<<(512*512)/256, 256, 0, stream>>>(Wq, WqT, 512);
    wt_kernel<<<(1024*512)/256, 256, 0, stream>>>(Wk, WkT, 1024);
    wt_kernel<<<(1024*512)/256, 256, 0, stream>>>(Wv, WvT, 1024);
    wt_kernel<<<(512*512)/256, 256, 0, stream>>>(Wo, WoT, 512);

    dim3 gp(8192 / 64, 512 / 64);
    gemm_proj<0, false><<<gp, 256, 0, stream>>>(query, WqT, bq, Qh, 512);
    gemm_proj<0, false><<<gp, 256, 0, stream>>>(key,   WkT, bk, Kh, 1024);
    gemm_proj<1, false><<<gp, 256, 0, stream>>>(value, WvT, bv, Vth, 1024);

    dim3 ga(TT / 64, BB * NH);
    attn_pv<<<ga, 256, 0, stream>>>(Qh, Kh, Vth, kpm, amask, attnW, AOf);

    gemm_proj<2, false><<<gp, 256, 0, stream>>>(AOf, WoT, bo, out0, 512);
}

// Round 21
// 351.728 us; speedup vs baseline: 1.2487x; 1.0033x over previous
//
#include <hip/hip_runtime.h>
#include <hip/hip_bf16.h>

#define BB 4
#define TT 2048
#define SSZ 2048
#define DQq 512
#define NH 8
#define HDim 64

typedef __attribute__((ext_vector_type(8))) short short8;
typedef __attribute__((ext_vector_type(4))) short bf16x4;
typedef __attribute__((ext_vector_type(4))) float f32x4;
typedef __attribute__((ext_vector_type(4))) int i32x4;

__device__ __forceinline__ short f2bf(float f) {
    union { float f; unsigned u; } v; v.f = f;
    unsigned r = v.u + 0x7fffu + ((v.u >> 16) & 1u);
    return (short)(r >> 16);
}

// ---------------- all four weight transposes in ONE launch (same per-element
// math as the round-5-verified wt_kernel)
__global__ void wt_all(const float* __restrict__ Wq, const float* __restrict__ Wk,
                       const float* __restrict__ Wv, const float* __restrict__ Wo,
                       short* __restrict__ WqT, short* __restrict__ WkT,
                       short* __restrict__ WvT, short* __restrict__ WoT) {
    int blk = blockIdx.x;
    const float* W; short* Wt; int Kd, base;
    if (blk < 1024)      { W = Wq; Wt = WqT; Kd = 512;  base = 0; }
    else if (blk < 3072) { W = Wk; Wt = WkT; Kd = 1024; base = 1024; }
    else if (blk < 5120) { W = Wv; Wt = WvT; Kd = 1024; base = 3072; }
    else                 { W = Wo; Wt = WoT; Kd = 512;  base = 5120; }
    int tid = (blk - base) * 256 + threadIdx.x;
    int n = tid / Kd, k = tid - n * Kd;
    Wt[tid] = f2bf(W[(size_t)k * DQq + n]);
}

// ---------------- projection GEMM v3: 64x64 tile (r5-verified fragments /
// epilogue), BK=64 staging -> barriers halved, 8 MFMA per barrier pair.
// Accumulation order unchanged (k ascending) -> bit-identical outputs.
template<int MODE, bool IN_BF16>
__global__ __launch_bounds__(256) void gemm_proj(
    const void* __restrict__ Xv, const short* __restrict__ Wt,
    const float* __restrict__ bias, void* __restrict__ Out, int Kd)
{
    __shared__ short As[64 * 72];
    __shared__ short Bs[64 * 72];
    int tid = threadIdx.x;
    int wave = tid >> 6, lane = tid & 63;
    int g = lane >> 4, r = lane & 15;
    int wm = wave >> 1, wn = wave & 1;
    int m0 = blockIdx.x * 64, n0 = blockIdx.y * 64;

    const float* Xf = (const float*)Xv;
    const short* Xb = (const short*)Xv;

    f32x4 acc[2][2];
    for (int a = 0; a < 2; ++a) for (int b2 = 0; b2 < 2; ++b2) acc[a][b2] = (f32x4){0.f,0.f,0.f,0.f};

    int lrow = tid >> 2, lk = (tid & 3) * 16;   // 64 rows, 4 threads/row, 16 elems each

    for (int kb = 0; kb < Kd; kb += 64) {
        short8 av0, av1;
        if (IN_BF16) {
            av0 = *(const short8*)(Xb + (size_t)(m0 + lrow) * Kd + kb + lk);
            av1 = *(const short8*)(Xb + (size_t)(m0 + lrow) * Kd + kb + lk + 8);
        } else {
            const f32x4* p = (const f32x4*)(Xf + (size_t)(m0 + lrow) * Kd + kb + lk);
            f32x4 x0 = p[0], x1 = p[1], x2 = p[2], x3 = p[3];
            av0[0]=f2bf(x0[0]); av0[1]=f2bf(x0[1]); av0[2]=f2bf(x0[2]); av0[3]=f2bf(x0[3]);
            av0[4]=f2bf(x1[0]); av0[5]=f2bf(x1[1]); av0[6]=f2bf(x1[2]); av0[7]=f2bf(x1[3]);
            av1[0]=f2bf(x2[0]); av1[1]=f2bf(x2[1]); av1[2]=f2bf(x2[2]); av1[3]=f2bf(x2[3]);
            av1[4]=f2bf(x3[0]); av1[5]=f2bf(x3[1]); av1[6]=f2bf(x3[2]); av1[7]=f2bf(x3[3]);
        }
        *(short8*)(As + lrow * 72 + lk) = av0;
        *(short8*)(As + lrow * 72 + lk + 8) = av1;
        short8 bv0 = *(const short8*)(Wt + (size_t)(n0 + lrow) * Kd + kb + lk);
        short8 bv1 = *(const short8*)(Wt + (size_t)(n0 + lrow) * Kd + kb + lk + 8);
        *(short8*)(Bs + lrow * 72 + lk) = bv0;
        *(short8*)(Bs + lrow * 72 + lk + 8) = bv1;
        __syncthreads();
        #pragma unroll
        for (int ks = 0; ks < 2; ++ks) {
            short8 af[2], bf[2];
            #pragma unroll
            for (int mi = 0; mi < 2; ++mi)
                af[mi] = *(short8*)(As + (wm*32 + mi*16 + r) * 72 + ks*32 + g*8);
            #pragma unroll
            for (int ni = 0; ni < 2; ++ni)
                bf[ni] = *(short8*)(Bs + (wn*32 + ni*16 + r) * 72 + ks*32 + g*8);
            #pragma unroll
            for (int mi = 0; mi < 2; ++mi)
                #pragma unroll
                for (int ni = 0; ni < 2; ++ni)
                    acc[mi][ni] = __builtin_amdgcn_mfma_f32_16x16x32_bf16(af[mi], bf[ni], acc[mi][ni], 0, 0, 0);
        }
        __syncthreads();
    }

    for (int mi = 0; mi < 2; ++mi)
      for (int ni = 0; ni < 2; ++ni)
        for (int i = 0; i < 4; ++i) {
            int m = m0 + wm*32 + mi*16 + g*4 + i;
            int n = n0 + wn*32 + ni*16 + r;
            float v = acc[mi][ni][i] + bias[n];
            if (MODE == 0) {
                int b = m >> 11, t = m & 2047, h = n >> 6, hd = n & 63;
                ((short*)Out)[((((size_t)b*NH + h)*TT + t) << 6) + hd] = f2bf(v);
            } else if (MODE == 1) {
                int b = m >> 11, t = m & 2047, h = n >> 6, hd = n & 63;
                ((short*)Out)[(((size_t)b*NH + h)*HDim + hd)*SSZ + t] = f2bf(v);
            } else {
                __builtin_nontemporal_store(v, (float*)Out + (size_t)m * DQq + n);
            }
        }
}

// ---------------- FUSED attention v8 (r20-verified, byte-identical)
#define WPITCH 264

__global__ __launch_bounds__(256) void attn_pv(
    const short* __restrict__ Q, const short* __restrict__ K,
    const short* __restrict__ Vt,
    const int* __restrict__ kpm, const float* __restrict__ amask,
    float* __restrict__ attnW, float* __restrict__ AO)
{
    __shared__ float s_wl[4][64];
    __shared__ float s_li[64];
    __shared__ short wch[64][WPITCH];

    int tid = threadIdx.x;
    int wave = tid >> 6, lane = tid & 63;
    int g = lane >> 4, r = lane & 15;
    int t0 = blockIdx.x * 64;
    int bh = blockIdx.y;
    int b = bh >> 3, h = bh & 7;

    const short* Qp = Q + ((size_t)bh * TT + t0) * HDim;
    const short* Kp = K + (size_t)bh * SSZ * HDim;

    short8 qf[4][2];
    #pragma unroll
    for (int tt = 0; tt < 4; ++tt) {
        qf[tt][0] = *(const short8*)(Qp + (size_t)(tt * 16 + r) * HDim + g * 8);
        qf[tt][1] = *(const short8*)(Qp + (size_t)(tt * 16 + r) * HDim + 32 + g * 8);
    }

    const float* amrow[4];
    #pragma unroll
    for (int tt = 0; tt < 4; ++tt)
        amrow[tt] = amask + (size_t)(t0 + tt * 16 + r) * SSZ;
    const int* kpmb = kpm + b * SSZ;

    int ws0 = wave * 512;
    float lrun[4] = {0.f, 0.f, 0.f, 0.f};
    for (int it = 0; it < 16; ++it) {
        int col0 = ws0 + it * 32;
        const short* kpA = Kp + (size_t)(col0 + r) * HDim;
        const short* kpB = Kp + (size_t)(col0 + 16 + r) * HDim;
        short8 kA0 = *(const short8*)(kpA + g * 8);
        short8 kA1 = *(const short8*)(kpA + 32 + g * 8);
        short8 kB0 = *(const short8*)(kpB + g * 8);
        short8 kB1 = *(const short8*)(kpB + 32 + g * 8);
        i32x4 okA = *(const i32x4*)(kpmb + col0 + g * 4);
        i32x4 okB = *(const i32x4*)(kpmb + col0 + 16 + g * 4);
        #pragma unroll
        for (int tt = 0; tt < 4; ++tt) {
            f32x4 sA = (f32x4){0.f,0.f,0.f,0.f}, sB = (f32x4){0.f,0.f,0.f,0.f};
            sA = __builtin_amdgcn_mfma_f32_16x16x32_bf16(kA0, qf[tt][0], sA, 0, 0, 0);
            sA = __builtin_amdgcn_mfma_f32_16x16x32_bf16(kA1, qf[tt][1], sA, 0, 0, 0);
            sB = __builtin_amdgcn_mfma_f32_16x16x32_bf16(kB0, qf[tt][0], sB, 0, 0, 0);
            sB = __builtin_amdgcn_mfma_f32_16x16x32_bf16(kB1, qf[tt][1], sB, 0, 0, 0);
            f32x4 amA = *(const f32x4*)(amrow[tt] + col0 + g * 4);
            f32x4 amB = *(const f32x4*)(amrow[tt] + col0 + 16 + g * 4);
            for (int i = 0; i < 4; ++i) {
                float vA = sA[i] * 0.125f + amA[i]; if (okA[i] == 0) vA = -1e30f;
                lrun[tt] += __expf(vA);
                float vB = sB[i] * 0.125f + amB[i]; if (okB[i] == 0) vB = -1e30f;
                lrun[tt] += __expf(vB);
            }
        }
    }
    #pragma unroll
    for (int tt = 0; tt < 4; ++tt) {
        lrun[tt] += __shfl_xor(lrun[tt], 16);
        lrun[tt] += __shfl_xor(lrun[tt], 32);
    }
    if (lane < 16) {
        #pragma unroll
        for (int tt = 0; tt < 4; ++tt)
            s_wl[wave][tt * 16 + lane] = lrun[tt];
    }
    __syncthreads();
    if (tid < 64)
        s_li[tid] = 1.0f / (s_wl[0][tid] + s_wl[1][tid] + s_wl[2][tid] + s_wl[3][tid]);
    __syncthreads();

    float li[4];
    float* wrow[4];
    #pragma unroll
    for (int tt = 0; tt < 4; ++tt) {
        li[tt] = s_li[tt * 16 + r];
        wrow[tt] = attnW + ((size_t)bh * TT + t0 + tt * 16 + r) * SSZ;
    }
    const short* vrow = Vt + ((size_t)bh * HDim + wave * 16 + r) * SSZ;
    f32x4 oacc[4];
    #pragma unroll
    for (int tt = 0; tt < 4; ++tt) oacc[tt] = (f32x4){0.f, 0.f, 0.f, 0.f};

    for (int ch = 0; ch < 8; ++ch) {
        for (int it = 0; it < 2; ++it) {
            int col0 = ch * 256 + wave * 64 + it * 32;
            const short* kpA = Kp + (size_t)(col0 + r) * HDim;
            const short* kpB = Kp + (size_t)(col0 + 16 + r) * HDim;
            short8 kA0 = *(const short8*)(kpA + g * 8);
            short8 kA1 = *(const short8*)(kpA + 32 + g * 8);
            short8 kB0 = *(const short8*)(kpB + g * 8);
            short8 kB1 = *(const short8*)(kpB + 32 + g * 8);
            i32x4 okA = *(const i32x4*)(kpmb + col0 + g * 4);
            i32x4 okB = *(const i32x4*)(kpmb + col0 + 16 + g * 4);
            int lcol = wave * 64 + it * 32;
            #pragma unroll
            for (int tt = 0; tt < 4; ++tt) {
                f32x4 sA = (f32x4){0.f,0.f,0.f,0.f}, sB = (f32x4){0.f,0.f,0.f,0.f};
                sA = __builtin_amdgcn_mfma_f32_16x16x32_bf16(kA0, qf[tt][0], sA, 0, 0, 0);
                sA = __builtin_amdgcn_mfma_f32_16x16x32_bf16(kA1, qf[tt][1], sA, 0, 0, 0);
                sB = __builtin_amdgcn_mfma_f32_16x16x32_bf16(kB0, qf[tt][0], sB, 0, 0, 0);
                sB = __builtin_amdgcn_mfma_f32_16x16x32_bf16(kB1, qf[tt][1], sB, 0, 0, 0);
                f32x4 amA = *(const f32x4*)(amrow[tt] + col0 + g * 4);
                f32x4 amB = *(const f32x4*)(amrow[tt] + col0 + 16 + g * 4);
                f32x4 wA, wB;
                bf16x4 pA, pB;
                for (int i = 0; i < 4; ++i) {
                    float vA = sA[i] * 0.125f + amA[i]; if (okA[i] == 0) vA = -1e30f;
                    wA[i] = __expf(vA) * li[tt]; pA[i] = f2bf(wA[i]);
                    float vB = sB[i] * 0.125f + amB[i]; if (okB[i] == 0) vB = -1e30f;
                    wB[i] = __expf(vB) * li[tt]; pB[i] = f2bf(wB[i]);
                }
                __builtin_nontemporal_store(wA, (f32x4*)(wrow[tt] + col0 + g * 4));
                __builtin_nontemporal_store(wB, (f32x4*)(wrow[tt] + col0 + 16 + g * 4));
                *(bf16x4*)&wch[tt * 16 + r][lcol + g * 4] = pA;
                *(bf16x4*)&wch[tt * 16 + r][lcol + 16 + g * 4] = pB;
            }
        }
        short8 vf[8];
        #pragma unroll
        for (int s = 0; s < 8; ++s)
            vf[s] = *(const short8*)(vrow + ch * 256 + s * 32 + g * 8);

        __syncthreads();

        #pragma unroll
        for (int s = 0; s < 8; ++s) {
            #pragma unroll
            for (int tt = 0; tt < 4; ++tt) {
                short8 wf = *(const short8*)&wch[tt * 16 + r][s * 32 + g * 8];
                oacc[tt] = __builtin_amdgcn_mfma_f32_16x16x32_bf16(wf, vf[s], oacc[tt], 0, 0, 0);
            }
        }
        __syncthreads();
    }

    #pragma unroll
    for (int tt = 0; tt < 4; ++tt)
        for (int i = 0; i < 4; ++i)
            __builtin_nontemporal_store(oacc[tt][i],
                AO + ((size_t)(b * TT + t0 + tt * 16 + g * 4 + i)) * DQq + h * HDim + wave * 16 + r);
}

extern "C" void kernel_launch(void* const* d_in, const int* in_sizes, int n_in,
                              void* d_out, int out_size, void* d_ws, size_t ws_size,
                              hipStream_t stream)
{
    const float* query = (const float*)d_in[0];
    const float* key   = (const float*)d_in[1];
    const float* value = (const float*)d_in[2];
    const int*   kpm   = (const int*)d_in[3];
    const float* amask = (const float*)d_in[4];
    const float* Wq = (const float*)d_in[5];
    const float* bq = (const float*)d_in[6];
    const float* Wk = (const float*)d_in[7];
    const float* bk = (const float*)d_in[8];
    const float* Wv = (const float*)d_in[9];
    const float* bv = (const float*)d_in[10];
    const float* Wo = (const float*)d_in[11];
    const float* bo = (const float*)d_in[12];

    char* ws = (char*)d_ws;
    short* WqT = (short*)ws;  ws += (size_t)512 * 512 * 2;
    short* WkT = (short*)ws;  ws += (size_t)512 * 1024 * 2;
    short* WvT = (short*)ws;  ws += (size_t)512 * 1024 * 2;
    short* WoT = (short*)ws;  ws += (size_t)512 * 512 * 2;
    short* Qh  = (short*)ws;  ws += (size_t)BB * NH * TT * HDim * 2;
    short* Kh  = (short*)ws;  ws += (size_t)BB * NH * SSZ * HDim * 2;
    short* Vth = (short*)ws;  ws += (size_t)BB * NH * HDim * SSZ * 2;
    float* AOf = (float*)ws;  ws += (size_t)BB * TT * DQq * 4;

    float* out0  = (float*)d_out;
    float* attnW = out0 + (size_t)BB * TT * DQq;

    wt_all<<<6144, 256, 0, stream>>>(Wq, Wk, Wv, Wo, WqT, WkT, WvT, WoT);

    dim3 gp(8192 / 64, 512 / 64);
    gemm_proj<0, false><<<gp, 256, 0, stream>>>(query, WqT, bq, Qh, 512);
    gemm_proj<0, false><<<gp, 256, 0, stream>>>(key,   WkT, bk, Kh, 1024);
    gemm_proj<1, false><<<gp, 256, 0, stream>>>(value, WvT, bv, Vth, 1024);

    dim3 ga(TT / 64, BB * NH);
    attn_pv<<<ga, 256, 0, stream>>>(Qh, Kh, Vth, kpm, amask, attnW, AOf);

    gemm_proj<2, false><<<gp, 256, 0, stream>>>(AOf, WoT, bo, out0, 512);
}